// Round 1
// baseline (679.201 us; speedup 1.0000x reference)
//
#include <hip/hip_runtime.h>
#include <cmath>

#define D 128
#define HID 64

__device__ __forceinline__ float silu_f(float x) { return x / (1.0f + expf(-x)); }

// order-preserving float <-> uint encode for atomicMax on floats
__device__ __forceinline__ unsigned fenc(float f) {
    unsigned u = __float_as_uint(f);
    return (u & 0x80000000u) ? ~u : (u | 0x80000000u);
}
__device__ __forceinline__ float fdec(unsigned e) {
    unsigned u = (e & 0x80000000u) ? (e & 0x7FFFFFFFu) : ~e;
    return __uint_as_float(u);
}

__global__ void k_copy(const float* __restrict__ src, float* __restrict__ dst, int n4) {
    int i = blockIdx.x * blockDim.x + threadIdx.x;
    if (i < n4) reinterpret_cast<float4*>(dst)[i] = reinterpret_cast<const float4*>(src)[i];
}

// transpose rw2 (64x64) -> rw2T so layer2 inner loop reads contiguous uniform rows
__global__ void k_prep(const float* __restrict__ rw2, float* __restrict__ rw2T) {
    int i = blockIdx.x * blockDim.x + threadIdx.x;
    if (i < HID * HID) rw2T[i] = rw2[(i & (HID - 1)) * HID + (i >> 6)];
}

// protection net: act = silu(x@pw1+pb1)@pw2+pb2 ; mask = act>0
__global__ __launch_bounds__(256) void k_protect(
    const float* __restrict__ states, const float* __restrict__ caps,
    const float* __restrict__ pw1, const float* __restrict__ pb1,
    const float* __restrict__ pw2, const float* __restrict__ pb2,
    unsigned* __restrict__ mask, unsigned* __restrict__ mlist,
    unsigned* __restrict__ counters, float* __restrict__ outmask, int N) {
    int n = blockIdx.x * blockDim.x + threadIdx.x;
    if (n >= N) return;
    float acc[HID];
#pragma unroll
    for (int j = 0; j < HID; j++) acc[j] = pb1[j];
    const float4* row = reinterpret_cast<const float4*>(states + (size_t)n * D);
    float4 xn = row[0];
    for (int ib = 0; ib < 32; ++ib) {
        float4 x = xn;
        if (ib + 1 < 32) xn = row[ib + 1];
        const float* w = pw1 + ib * 4 * HID;
#pragma unroll
        for (int u = 0; u < 4; u++) {
            float xv = (u == 0) ? x.x : (u == 1) ? x.y : (u == 2) ? x.z : x.w;
#pragma unroll
            for (int j = 0; j < HID; j++) acc[j] = fmaf(xv, w[u * HID + j], acc[j]);
        }
    }
    {   // capacity = input dim 128
        float xv = caps[n];
        const float* w = pw1 + 128 * HID;
#pragma unroll
        for (int j = 0; j < HID; j++) acc[j] = fmaf(xv, w[j], acc[j]);
    }
    float act = pb2[0];
#pragma unroll
    for (int j = 0; j < HID; j++) act = fmaf(silu_f(acc[j]), pw2[j], act);
    unsigned m = (act > 0.0f) ? 1u : 0u;
    mask[n] = m;
    outmask[n] = m ? 1.0f : 0.0f;
    if (m) {
        unsigned slot = atomicAdd(&counters[1], 1u);
        mlist[slot] = (unsigned)n;
    }
}

// compact edges with emask = mask[src] && !mask[tgt]
__global__ void k_compact(const int* __restrict__ ei, const unsigned* __restrict__ mask,
                          unsigned* __restrict__ act_eid, unsigned* __restrict__ counters, int E) {
    int e = blockIdx.x * blockDim.x + threadIdx.x;
    if (e >= E) return;
    int s = ei[e], t = ei[E + e];
    if (mask[s] && !mask[t]) {
        unsigned slot = atomicAdd(&counters[0], 1u);
        act_eid[slot] = (unsigned)e;
    }
}

// redistribution MLP on active edges only (lane-per-edge, uniform weight loads)
__global__ __launch_bounds__(256) void k_edge_mlp(
    const float* __restrict__ states, const int* __restrict__ ei,
    const float* __restrict__ rw1, const float* __restrict__ rb1,
    const float* __restrict__ rw2T, const float* __restrict__ rb2,
    const float* __restrict__ rw3, const float* __restrict__ rb3,
    const unsigned* __restrict__ act_eid, const unsigned* __restrict__ counters,
    float* __restrict__ rawbuf, unsigned* __restrict__ segmax, int E) {
    unsigned t = blockIdx.x * blockDim.x + threadIdx.x;
    if (t >= counters[0]) return;
    int e = (int)act_eid[t];
    int s = ei[e];
    float h[HID];
#pragma unroll
    for (int j = 0; j < HID; j++) h[j] = rb1[j];
    const float4* rowA = reinterpret_cast<const float4*>(states + (size_t)s * D);
    const float4* rowB = reinterpret_cast<const float4*>(states + (size_t)ei[E + e] * D);
    for (int half = 0; half < 2; ++half) {
        const float4* row = half ? rowB : rowA;
        const float* wbase = rw1 + half * D * HID;
        float4 xn = row[0];
        for (int ib = 0; ib < 32; ++ib) {
            float4 x = xn;
            if (ib + 1 < 32) xn = row[ib + 1];
            const float* w = wbase + ib * 4 * HID;
#pragma unroll
            for (int u = 0; u < 4; u++) {
                float xv = (u == 0) ? x.x : (u == 1) ? x.y : (u == 2) ? x.z : x.w;
#pragma unroll
                for (int j = 0; j < HID; j++) h[j] = fmaf(xv, w[u * HID + j], h[j]);
            }
        }
    }
#pragma unroll
    for (int j = 0; j < HID; j++) h[j] = silu_f(h[j]);
    float raw = rb3[0];
    for (int j = 0; j < HID; j++) {  // layer2+layer3 fused; h[k] statically indexed
        const float* w = rw2T + j * HID;
        float s0 = rb2[j], s1 = 0.f, s2 = 0.f, s3 = 0.f;
#pragma unroll
        for (int k = 0; k < HID; k += 4) {
            s0 = fmaf(h[k + 0], w[k + 0], s0);
            s1 = fmaf(h[k + 1], w[k + 1], s1);
            s2 = fmaf(h[k + 2], w[k + 2], s2);
            s3 = fmaf(h[k + 3], w[k + 3], s3);
        }
        float h2 = silu_f((s0 + s1) + (s2 + s3));
        raw = fmaf(h2, rw3[j], raw);
    }
    rawbuf[t] = raw;
    atomicMax(&segmax[s], fenc(raw));
}

__global__ void k_exp(const int* __restrict__ ei, const unsigned* __restrict__ act_eid,
                      const unsigned* __restrict__ counters, const unsigned* __restrict__ segmax,
                      float* __restrict__ rawbuf, float* __restrict__ denom, int E) {
    unsigned t = blockIdx.x * blockDim.x + threadIdx.x;
    if (t >= counters[0]) return;
    int e = (int)act_eid[t];
    int s = ei[e];
    float ev = expf(rawbuf[t] - fdec(segmax[s]));
    rawbuf[t] = ev;
    atomicAdd(&denom[s], ev);
}

// wave-per-active-edge: out[tgt] += w * states[src]
__global__ __launch_bounds__(256) void k_scatter(
    const float* __restrict__ states, const int* __restrict__ ei,
    const unsigned* __restrict__ act_eid, const unsigned* __restrict__ counters,
    const float* __restrict__ rawbuf, const float* __restrict__ denom,
    float* __restrict__ out, int E) {
    unsigned w = blockIdx.x * (blockDim.x >> 6) + (threadIdx.x >> 6);
    unsigned lane = threadIdx.x & 63u;
    if (w >= counters[0]) return;
    int e = (int)act_eid[w];
    int s = ei[e], tg = ei[E + e];
    float wt = rawbuf[w] / denom[s];
    const float* srow = states + (size_t)s * D;
    float* orow = out + (size_t)tg * D;
    atomicAdd(&orow[lane], wt * srow[lane]);
    atomicAdd(&orow[lane + 64], wt * srow[lane + 64]);
}

// failed nodes: out = tanh(redist @ tw + tb) * 0.05  (thread-per-masked-node)
__global__ __launch_bounds__(256) void k_jump(
    const float* __restrict__ tw, const float* __restrict__ tb,
    const unsigned* __restrict__ mlist, const unsigned* __restrict__ counters,
    float* __restrict__ out) {
    unsigned t = blockIdx.x * blockDim.x + threadIdx.x;
    if (t >= counters[1]) return;
    int n = (int)mlist[t];
    float* row = out + (size_t)n * D;
    float acc[D];
#pragma unroll
    for (int d = 0; d < D; d++) acc[d] = tb[d];
    const float4* r4 = reinterpret_cast<const float4*>(row);
    float4 xn = r4[0];
    for (int ib = 0; ib < 32; ++ib) {
        float4 x = xn;
        if (ib + 1 < 32) xn = r4[ib + 1];
        const float* w = tw + ib * 4 * D;
#pragma unroll
        for (int u = 0; u < 4; u++) {
            float xv = (u == 0) ? x.x : (u == 1) ? x.y : (u == 2) ? x.z : x.w;
#pragma unroll
            for (int d = 0; d < D; d++) acc[d] = fmaf(xv, w[u * D + d], acc[d]);
        }
    }
#pragma unroll
    for (int d = 0; d < D; d++) acc[d] = tanhf(acc[d]) * 0.05f;
    float4* w4 = reinterpret_cast<float4*>(row);
#pragma unroll
    for (int ib = 0; ib < 32; ++ib) {
        float4 v;
        v.x = acc[ib * 4 + 0]; v.y = acc[ib * 4 + 1];
        v.z = acc[ib * 4 + 2]; v.w = acc[ib * 4 + 3];
        w4[ib] = v;
    }
}

extern "C" void kernel_launch(void* const* d_in, const int* in_sizes, int n_in,
                              void* d_out, int out_size, void* d_ws, size_t ws_size,
                              hipStream_t stream) {
    const float* states = (const float*)d_in[0];
    const float* caps   = (const float*)d_in[1];
    const int*   ei     = (const int*)d_in[2];
    const float* rw1 = (const float*)d_in[3];  const float* rb1 = (const float*)d_in[4];
    const float* rw2 = (const float*)d_in[5];  const float* rb2 = (const float*)d_in[6];
    const float* rw3 = (const float*)d_in[7];  const float* rb3 = (const float*)d_in[8];
    const float* pw1 = (const float*)d_in[9];  const float* pb1 = (const float*)d_in[10];
    const float* pw2 = (const float*)d_in[11]; const float* pb2 = (const float*)d_in[12];
    const float* tw  = (const float*)d_in[13]; const float* tb  = (const float*)d_in[14];
    const int N = in_sizes[1];
    const int E = in_sizes[2] / 2;
    float* out = (float*)d_out;

    // ws layout (u32 units): [0..3] counters | segmax N | denom N | mask N | mlist N | act_eid E | rawbuf E | rw2T 4096
    unsigned* ws       = (unsigned*)d_ws;
    unsigned* counters = ws;
    unsigned* segmax   = ws + 4;
    float*    denom    = (float*)(ws + 4 + (size_t)N);
    unsigned* mask     = ws + 4 + 2 * (size_t)N;
    unsigned* mlist    = ws + 4 + 3 * (size_t)N;
    unsigned* act_eid  = ws + 4 + 4 * (size_t)N;
    float*    rawbuf   = (float*)(ws + 4 + 4 * (size_t)N + (size_t)E);
    float*    rw2T     = (float*)(ws + 4 + 4 * (size_t)N + 2 * (size_t)E);

    // zero counters + segmax + denom (contiguous prefix)
    hipMemsetAsync(d_ws, 0, (size_t)(4 + 2 * (size_t)N) * 4, stream);

    k_prep<<<(HID * HID + 255) / 256, 256, 0, stream>>>(rw2, rw2T);
    const int n4 = N * D / 4;
    k_copy<<<(n4 + 255) / 256, 256, 0, stream>>>(states, out, n4);
    k_protect<<<(N + 255) / 256, 256, 0, stream>>>(states, caps, pw1, pb1, pw2, pb2,
                                                   mask, mlist, counters, out + (size_t)N * D, N);
    k_compact<<<(E + 255) / 256, 256, 0, stream>>>(ei, mask, act_eid, counters, E);
    k_edge_mlp<<<(E + 255) / 256, 256, 0, stream>>>(states, ei, rw1, rb1, rw2T, rb2, rw3, rb3,
                                                    act_eid, counters, rawbuf, segmax, E);
    k_exp<<<(E + 255) / 256, 256, 0, stream>>>(ei, act_eid, counters, segmax, rawbuf, denom, E);
    k_scatter<<<(E + 3) / 4, 256, 0, stream>>>(states, ei, act_eid, counters, rawbuf, denom, out, E);
    k_jump<<<(N + 255) / 256, 256, 0, stream>>>(tw, tb, mlist, counters, out);
}

// Round 2
// 516.020 us; speedup vs baseline: 1.3162x; 1.3162x over previous
//
#include <hip/hip_runtime.h>
#include <cmath>

#define D 128
#define HID 64

__device__ __forceinline__ float silu_f(float x) { return x / (1.0f + expf(-x)); }

__device__ __forceinline__ float4 fma4(float a, float4 w, float4 c) {
    c.x = fmaf(a, w.x, c.x); c.y = fmaf(a, w.y, c.y);
    c.z = fmaf(a, w.z, c.z); c.w = fmaf(a, w.w, c.w);
    return c;
}
__device__ __forceinline__ float4 silu4(float4 v) {
    v.x = silu_f(v.x); v.y = silu_f(v.y); v.z = silu_f(v.z); v.w = silu_f(v.w);
    return v;
}

// order-preserving float <-> uint encode for atomicMax on floats
__device__ __forceinline__ unsigned fenc(float f) {
    unsigned u = __float_as_uint(f);
    return (u & 0x80000000u) ? ~u : (u | 0x80000000u);
}
__device__ __forceinline__ float fdec(unsigned e) {
    unsigned u = (e & 0x80000000u) ? (e & 0x7FFFFFFFu) : ~e;
    return __uint_as_float(u);
}

// accumulate 64 hidden units (16 named float4) with one input scalar
#define ACC16(xv, wp) { const float4* _w4 = reinterpret_cast<const float4*>(wp); \
    h0  = fma4(xv, _w4[0],  h0);  h1  = fma4(xv, _w4[1],  h1);  \
    h2  = fma4(xv, _w4[2],  h2);  h3  = fma4(xv, _w4[3],  h3);  \
    h4  = fma4(xv, _w4[4],  h4);  h5  = fma4(xv, _w4[5],  h5);  \
    h6  = fma4(xv, _w4[6],  h6);  h7  = fma4(xv, _w4[7],  h7);  \
    h8  = fma4(xv, _w4[8],  h8);  h9  = fma4(xv, _w4[9],  h9);  \
    h10 = fma4(xv, _w4[10], h10); h11 = fma4(xv, _w4[11], h11); \
    h12 = fma4(xv, _w4[12], h12); h13 = fma4(xv, _w4[13], h13); \
    h14 = fma4(xv, _w4[14], h14); h15 = fma4(xv, _w4[15], h15); }

#define SILU16() { h0 = silu4(h0); h1 = silu4(h1); h2 = silu4(h2); h3 = silu4(h3); \
    h4 = silu4(h4); h5 = silu4(h5); h6 = silu4(h6); h7 = silu4(h7); \
    h8 = silu4(h8); h9 = silu4(h9); h10 = silu4(h10); h11 = silu4(h11); \
    h12 = silu4(h12); h13 = silu4(h13); h14 = silu4(h14); h15 = silu4(h15); }

#define INIT16(bp) { const float4* _b4 = reinterpret_cast<const float4*>(bp); \
    h0 = _b4[0]; h1 = _b4[1]; h2 = _b4[2]; h3 = _b4[3]; \
    h4 = _b4[4]; h5 = _b4[5]; h6 = _b4[6]; h7 = _b4[7]; \
    h8 = _b4[8]; h9 = _b4[9]; h10 = _b4[10]; h11 = _b4[11]; \
    h12 = _b4[12]; h13 = _b4[13]; h14 = _b4[14]; h15 = _b4[15]; }

// dot with 4 partial sums, k%4 -> s0..s3 (matches round-1 ordering)
__device__ __forceinline__ void fd4(float4 h, float4 w, float& s0, float& s1, float& s2, float& s3) {
    s0 = fmaf(h.x, w.x, s0); s1 = fmaf(h.y, w.y, s1);
    s2 = fmaf(h.z, w.z, s2); s3 = fmaf(h.w, w.w, s3);
}
#define FD16(w4) { fd4(h0, w4[0], s0, s1, s2, s3);  fd4(h1, w4[1], s0, s1, s2, s3);  \
    fd4(h2, w4[2], s0, s1, s2, s3);  fd4(h3, w4[3], s0, s1, s2, s3);  \
    fd4(h4, w4[4], s0, s1, s2, s3);  fd4(h5, w4[5], s0, s1, s2, s3);  \
    fd4(h6, w4[6], s0, s1, s2, s3);  fd4(h7, w4[7], s0, s1, s2, s3);  \
    fd4(h8, w4[8], s0, s1, s2, s3);  fd4(h9, w4[9], s0, s1, s2, s3);  \
    fd4(h10, w4[10], s0, s1, s2, s3); fd4(h11, w4[11], s0, s1, s2, s3); \
    fd4(h12, w4[12], s0, s1, s2, s3); fd4(h13, w4[13], s0, s1, s2, s3); \
    fd4(h14, w4[14], s0, s1, s2, s3); fd4(h15, w4[15], s0, s1, s2, s3); }

// serial silu-dot (matches round-1 serial j order for mask stability)
__device__ __forceinline__ float accdot(float4 h, float4 w, float act) {
    act = fmaf(silu_f(h.x), w.x, act);
    act = fmaf(silu_f(h.y), w.y, act);
    act = fmaf(silu_f(h.z), w.z, act);
    act = fmaf(silu_f(h.w), w.w, act);
    return act;
}

__global__ void k_copy(const float* __restrict__ src, float* __restrict__ dst, int n4) {
    int i = blockIdx.x * blockDim.x + threadIdx.x;
    if (i < n4) reinterpret_cast<float4*>(dst)[i] = reinterpret_cast<const float4*>(src)[i];
}

// transpose rw2 (64x64) -> rw2T
__global__ void k_prep(const float* __restrict__ rw2, float* __restrict__ rw2T) {
    int i = blockIdx.x * blockDim.x + threadIdx.x;
    if (i < HID * HID) rw2T[i] = rw2[(i & (HID - 1)) * HID + (i >> 6)];
}

// protection net: act = silu(x@pw1+pb1)@pw2+pb2 ; mask = act>0
__global__ __launch_bounds__(256) void k_protect(
    const float* __restrict__ states, const float* __restrict__ caps,
    const float* __restrict__ pw1, const float* __restrict__ pb1,
    const float* __restrict__ pw2, const float* __restrict__ pb2,
    unsigned* __restrict__ mask, unsigned* __restrict__ mlist,
    unsigned* __restrict__ counters, float* __restrict__ outmask, int N) {
    int n = blockIdx.x * blockDim.x + threadIdx.x;
    if (n >= N) return;
    float4 h0, h1, h2, h3, h4, h5, h6, h7, h8, h9, h10, h11, h12, h13, h14, h15;
    INIT16(pb1);
    const float4* row = reinterpret_cast<const float4*>(states + (size_t)n * D);
    for (int ib = 0; ib < 32; ++ib) {
        float4 x = row[ib];
        const float* w = pw1 + ib * 4 * HID;
        ACC16(x.x, w); ACC16(x.y, w + HID); ACC16(x.z, w + 2 * HID); ACC16(x.w, w + 3 * HID);
    }
    { float xv = caps[n]; ACC16(xv, pw1 + 128 * HID); }
    const float4* w2 = reinterpret_cast<const float4*>(pw2);
    float act = pb2[0];
    act = accdot(h0, w2[0], act);   act = accdot(h1, w2[1], act);
    act = accdot(h2, w2[2], act);   act = accdot(h3, w2[3], act);
    act = accdot(h4, w2[4], act);   act = accdot(h5, w2[5], act);
    act = accdot(h6, w2[6], act);   act = accdot(h7, w2[7], act);
    act = accdot(h8, w2[8], act);   act = accdot(h9, w2[9], act);
    act = accdot(h10, w2[10], act); act = accdot(h11, w2[11], act);
    act = accdot(h12, w2[12], act); act = accdot(h13, w2[13], act);
    act = accdot(h14, w2[14], act); act = accdot(h15, w2[15], act);
    unsigned m = (act > 0.0f) ? 1u : 0u;
    mask[n] = m;
    outmask[n] = m ? 1.0f : 0.0f;
    if (m) {
        unsigned slot = atomicAdd(&counters[1], 1u);
        mlist[slot] = (unsigned)n;
    }
}

// compact edges with emask = mask[src] && !mask[tgt]
__global__ void k_compact(const int* __restrict__ ei, const unsigned* __restrict__ mask,
                          unsigned* __restrict__ act_eid, unsigned* __restrict__ counters, int E) {
    int e = blockIdx.x * blockDim.x + threadIdx.x;
    if (e >= E) return;
    int s = ei[e], t = ei[E + e];
    if (mask[s] && !mask[t]) {
        unsigned slot = atomicAdd(&counters[0], 1u);
        act_eid[slot] = (unsigned)e;
    }
}

// redistribution MLP on active edges only
__global__ __launch_bounds__(256) void k_edge_mlp(
    const float* __restrict__ states, const int* __restrict__ ei,
    const float* __restrict__ rw1, const float* __restrict__ rb1,
    const float* __restrict__ rw2T, const float* __restrict__ rb2,
    const float* __restrict__ rw3, const float* __restrict__ rb3,
    const unsigned* __restrict__ act_eid, const unsigned* __restrict__ counters,
    float* __restrict__ rawbuf, unsigned* __restrict__ segmax, int E) {
    unsigned t = blockIdx.x * blockDim.x + threadIdx.x;
    if (t >= counters[0]) return;
    int e = (int)act_eid[t];
    int s = ei[e], tg = ei[E + e];
    float4 h0, h1, h2, h3, h4, h5, h6, h7, h8, h9, h10, h11, h12, h13, h14, h15;
    INIT16(rb1);
    const float4* rowA = reinterpret_cast<const float4*>(states + (size_t)s * D);
    const float4* rowB = reinterpret_cast<const float4*>(states + (size_t)tg * D);
    for (int half = 0; half < 2; ++half) {
        const float4* row = half ? rowB : rowA;
        const float* wb = rw1 + half * (D * HID);
        for (int ib = 0; ib < 32; ++ib) {
            float4 x = row[ib];
            const float* w = wb + ib * 4 * HID;
            ACC16(x.x, w); ACC16(x.y, w + HID); ACC16(x.z, w + 2 * HID); ACC16(x.w, w + 3 * HID);
        }
    }
    SILU16();
    float raw = rb3[0];
    for (int j = 0; j < HID; ++j) {
        const float4* w4 = reinterpret_cast<const float4*>(rw2T + j * HID);
        float s0 = rb2[j], s1 = 0.f, s2 = 0.f, s3 = 0.f;
        FD16(w4);
        float h2v = silu_f((s0 + s1) + (s2 + s3));
        raw = fmaf(h2v, rw3[j], raw);
    }
    rawbuf[t] = raw;
    atomicMax(&segmax[s], fenc(raw));
}

__global__ void k_exp(const int* __restrict__ ei, const unsigned* __restrict__ act_eid,
                      const unsigned* __restrict__ counters, const unsigned* __restrict__ segmax,
                      float* __restrict__ rawbuf, float* __restrict__ denom, int E) {
    unsigned t = blockIdx.x * blockDim.x + threadIdx.x;
    if (t >= counters[0]) return;
    int e = (int)act_eid[t];
    int s = ei[e];
    float ev = expf(rawbuf[t] - fdec(segmax[s]));
    rawbuf[t] = ev;
    atomicAdd(&denom[s], ev);
}

// wave-per-active-edge: out[tgt] += w * states[src]
__global__ __launch_bounds__(256) void k_scatter(
    const float* __restrict__ states, const int* __restrict__ ei,
    const unsigned* __restrict__ act_eid, const unsigned* __restrict__ counters,
    const float* __restrict__ rawbuf, const float* __restrict__ denom,
    float* __restrict__ out, int E) {
    unsigned w = blockIdx.x * (blockDim.x >> 6) + (threadIdx.x >> 6);
    unsigned lane = threadIdx.x & 63u;
    if (w >= counters[0]) return;
    int e = (int)act_eid[w];
    int s = ei[e], tg = ei[E + e];
    float wt = rawbuf[w] / denom[s];
    const float* srow = states + (size_t)s * D;
    float* orow = out + (size_t)tg * D;
    atomicAdd(&orow[lane], wt * srow[lane]);
    atomicAdd(&orow[lane + 64], wt * srow[lane + 64]);
}

// failed nodes: out = tanh(redist @ tw + tb) * 0.05
// 2 nodes per 256-thread block; thread-per-(node,dim); LDS-staged input row
// (also removes the in-place read/write race)
__global__ __launch_bounds__(256) void k_jump(
    const float* __restrict__ tw, const float* __restrict__ tb,
    const unsigned* __restrict__ mlist, const unsigned* __restrict__ counters,
    float* __restrict__ out) {
    __shared__ float xs[2][D];
    unsigned g = threadIdx.x >> 7;           // node group within block
    unsigned d = threadIdx.x & 127u;         // output dim
    unsigned slot = blockIdx.x * 2 + g;
    bool valid = slot < counters[1];
    int n = valid ? (int)mlist[slot] : 0;
    float* row = out + (size_t)n * D;
    if (valid) xs[g][d] = row[d];
    __syncthreads();
    if (!valid) return;
    float acc = tb[d];
    const float* ws = &xs[g][0];
    // serial over k (matches ref accumulate order); weight reads coalesced over d
    for (int k = 0; k < D; k += 4) {
        acc = fmaf(ws[k + 0], tw[(k + 0) * D + d], acc);
        acc = fmaf(ws[k + 1], tw[(k + 1) * D + d], acc);
        acc = fmaf(ws[k + 2], tw[(k + 2) * D + d], acc);
        acc = fmaf(ws[k + 3], tw[(k + 3) * D + d], acc);
    }
    row[d] = tanhf(acc) * 0.05f;
}

extern "C" void kernel_launch(void* const* d_in, const int* in_sizes, int n_in,
                              void* d_out, int out_size, void* d_ws, size_t ws_size,
                              hipStream_t stream) {
    const float* states = (const float*)d_in[0];
    const float* caps   = (const float*)d_in[1];
    const int*   ei     = (const int*)d_in[2];
    const float* rw1 = (const float*)d_in[3];  const float* rb1 = (const float*)d_in[4];
    const float* rw2 = (const float*)d_in[5];  const float* rb2 = (const float*)d_in[6];
    const float* rw3 = (const float*)d_in[7];  const float* rb3 = (const float*)d_in[8];
    const float* pw1 = (const float*)d_in[9];  const float* pb1 = (const float*)d_in[10];
    const float* pw2 = (const float*)d_in[11]; const float* pb2 = (const float*)d_in[12];
    const float* tw  = (const float*)d_in[13]; const float* tb  = (const float*)d_in[14];
    const int N = in_sizes[1];
    const int E = in_sizes[2] / 2;
    float* out = (float*)d_out;

    // ws layout (u32 units): [0..3] counters | segmax N | denom N | mask N | mlist N | act_eid E | rawbuf E | rw2T 4096
    unsigned* ws       = (unsigned*)d_ws;
    unsigned* counters = ws;
    unsigned* segmax   = ws + 4;
    float*    denom    = (float*)(ws + 4 + (size_t)N);
    unsigned* mask     = ws + 4 + 2 * (size_t)N;
    unsigned* mlist    = ws + 4 + 3 * (size_t)N;
    unsigned* act_eid  = ws + 4 + 4 * (size_t)N;
    float*    rawbuf   = (float*)(ws + 4 + 4 * (size_t)N + (size_t)E);
    float*    rw2T     = (float*)(ws + 4 + 4 * (size_t)N + 2 * (size_t)E);

    hipMemsetAsync(d_ws, 0, (size_t)(4 + 2 * (size_t)N) * 4, stream);

    k_prep<<<(HID * HID + 255) / 256, 256, 0, stream>>>(rw2, rw2T);
    const int n4 = N * D / 4;
    k_copy<<<(n4 + 255) / 256, 256, 0, stream>>>(states, out, n4);
    k_protect<<<(N + 255) / 256, 256, 0, stream>>>(states, caps, pw1, pb1, pw2, pb2,
                                                   mask, mlist, counters, out + (size_t)N * D, N);
    k_compact<<<(E + 255) / 256, 256, 0, stream>>>(ei, mask, act_eid, counters, E);
    k_edge_mlp<<<(E + 255) / 256, 256, 0, stream>>>(states, ei, rw1, rb1, rw2T, rb2, rw3, rb3,
                                                    act_eid, counters, rawbuf, segmax, E);
    k_exp<<<(E + 255) / 256, 256, 0, stream>>>(ei, act_eid, counters, segmax, rawbuf, denom, E);
    k_scatter<<<(E + 3) / 4, 256, 0, stream>>>(states, ei, act_eid, counters, rawbuf, denom, out, E);
    k_jump<<<(N + 1) / 2, 256, 0, stream>>>(tw, tb, mlist, counters, out);
}